// Round 5
// baseline (17.862 us; speedup 1.0000x reference)
//
#include <hip/hip_runtime.h>
#include <math.h>

#define IMG_OUT 64
#define WIN 24          // band window (channels), shared by 4 pixels of a z-seg
#define STRIDE 25       // LDS row stride (odd -> conflict-free)

__global__ __launch_bounds__(128, 6) void cube_sim_kernel(
    const float* __restrict__ freqs,
    const float* __restrict__ p_incl,
    const float* __restrict__ p_rot,
    const float* __restrict__ p_lb,
    const float* __restrict__ p_vshift,
    const float* __restrict__ p_vmax,
    const float* __restrict__ p_rturn,
    const float* __restrict__ p_i0,
    const float* __restrict__ p_rd,
    const float* __restrict__ p_hz,
    float* __restrict__ out)
{
    const int t    = threadIdx.x;        // 0..127
    const int w    = t >> 6;             // wave 0/1
    const int lane = t & 63;
    const int p    = lane >> 4;          // internal pixel 0..3
    const int zs   = (w << 4) | (lane & 15);   // z-segment 0..31 (4 z each)
    const int xo = blockIdx.x, yo = blockIdx.y;

    __shared__ float  s_band[32 * STRIDE + 16];  // +pad for masked OOB reads
    __shared__ int    s_base[32];
    __shared__ float4 s_part4[2][16];

    // ---- scalars ----
    const float incl   = p_incl[0];
    const float rot    = p_rot[0];
    const float lb     = p_lb[0];
    const float vshift = p_vshift[0];
    const float vmx    = p_vmax[0];
    const float rturn  = p_rturn[0];
    const float i0     = p_i0[0];
    const float rd     = p_rd[0];
    const float hz     = p_hz[0];

    const float LOG2E = 1.4426950408889634f;
    const float ci = cosf(incl), si = sinf(incl);
    const float cr = cosf(rot),  sr = sinf(rot);

    const float C_KMS = 299792.458f;
    const float F0    = 230.538f;
    const float f_lo  = freqs[0];
    const float df    = (freqs[15] - f_lo) * (1.0f / 63.0f);
    const float beta  = C_KMS * df / F0;                      // km/s per fine channel
    const float alpha = C_KMS * (F0 - f_lo + 2.0f * df) / F0 - vshift;
    const float inv_beta = 1.0f / beta;

    const float sgs  = sqrtf(LOG2E) / lb;  // d' = d_kms*sgs -> G = exp2(-d'^2)
    const float bp   = beta * sgs;         // channel pitch (d' units)
    const float bp2  = 2.0f * bp;
    const float bpsq = bp * bp;
    const float q    = exp2f(-2.0f * bpsq);   // uniform ratio-of-ratios

    const float step = 2000.0f / 127.0f;
    const float inv_rturn = 1.0f / rturn;
    const float cA_r = -LOG2E / rd;
    const float cA_z = -LOG2E / hz;
    const float two_over_pi = 0.636619772367581f;

    // ---- geometry: this lane's pixel, 4 z-points ----
    const float x = -1000.0f + (float)(2 * xo + (p >> 1)) * step;
    const float y = -1000.0f + (float)(2 * yo + (p & 1)) * step;
    const float rx = cr * x - sr * y;
    const float u0 = sr * x + cr * y;
    const float crx = -si * vmx * two_over_pi * rx;  // v_los = crx*atan(rad/rt)/rad

    float v[4], A[4];
    #pragma unroll
    for (int k = 0; k < 4; ++k) {
        const float z  = -1000.0f + (float)(zs * 4 + k) * step;
        const float ry = ci * u0 - si * z;
        const float rz = si * u0 + ci * z;
        const float r2 = rx * rx + ry * ry + 1e-12f;
        const float ir = __builtin_amdgcn_rsqf(r2);
        const float rad = r2 * ir;
        v[k] = crx * atanf(rad * inv_rturn) * ir;
        A[k] = fmaf(rad, cA_r, fabsf(rz) * cA_z);   // log2 intensity (i0 excluded)
    }

    // ---- common band base across 4 pixels of this z-seg ----
    float vlo = fminf(fminf(v[0], v[1]), fminf(v[2], v[3]));
    float vhi = fmaxf(fmaxf(v[0], v[1]), fmaxf(v[2], v[3]));
    vlo = fminf(vlo, __shfl_xor(vlo, 16)); vlo = fminf(vlo, __shfl_xor(vlo, 32));
    vhi = fmaxf(vhi, __shfl_xor(vhi, 16)); vhi = fmaxf(vhi, __shfl_xor(vhi, 32));
    int base = (int)rintf((alpha - 0.5f * (vlo + vhi)) * inv_beta) - (WIN / 2);
    base = min(max(base, 0), 64 - WIN);
    const float Wb = fmaf(-beta, (float)base, alpha);   // km/s diff at channel `base`

    // ---- 4z x 24ch KDE via multiplicative recurrence (2 exp2 per z) ----
    float acc[WIN];
    #pragma unroll
    for (int j = 0; j < WIN; ++j) acc[j] = 0.0f;

    #pragma unroll
    for (int k = 0; k < 4; ++k) {
        const float Wk = sgs * (Wb - v[k]);
        float G = __builtin_amdgcn_exp2f(fmaf(-Wk, Wk, A[k]));   // exp2(A - W^2)
        float u = __builtin_amdgcn_exp2f(fmaf(bp2, Wk, -bpsq));  // step ratio
        #pragma unroll
        for (int j = 0; j < WIN; ++j) {
            acc[j] += G;
            G *= u;
            u *= q;
        }
    }

    // ---- merge 4 pixels (aligned bands) in-register ----
    #pragma unroll
    for (int j = 0; j < WIN; ++j) {
        acc[j] += __shfl_xor(acc[j], 16);
        acc[j] += __shfl_xor(acc[j], 32);
    }

    // ---- publish merged rows (p==0 lanes), bases ----
    if (p == 0) {
        #pragma unroll
        for (int j = 0; j < WIN; ++j) s_band[zs * STRIDE + j] = acc[j];
        s_base[zs] = base;
    }
    __syncthreads();

    // ---- gather: thread (c = t&63, h = t>>6) sums rows h*16..h*16+15 ----
    const int c = t & 63;
    const int h = t >> 6;
    const int myb = s_base[lane & 31];
    float s = 0.0f;
    #pragma unroll
    for (int j = 0; j < 16; ++j) {
        const int r = h * 16 + j;                       // wave-uniform
        const int b = __builtin_amdgcn_readlane(myb, r);
        const int off = c - b;
        const float val = s_band[r * STRIDE + (off & 31)];
        s += ((unsigned)off < (unsigned)WIN) ? val : 0.0f;
    }
    ((float*)&s_part4[h])[c] = s;
    __syncthreads();

    // ---- pool 4 sub-channels x 2 halves, scale, write ----
    if (t < 16) {
        const float4 a = s_part4[0][t];
        const float4 b = s_part4[1][t];
        const float sum = ((a.x + a.y) + (a.z + a.w)) + ((b.x + b.y) + (b.z + b.w));
        const float scale = i0 * 0.0625f / sqrtf(6.283185307179586f * lb * lb);
        out[t * (IMG_OUT * IMG_OUT) + xo * IMG_OUT + yo] = sum * scale;
    }
}

extern "C" void kernel_launch(void* const* d_in, const int* in_sizes, int n_in,
                              void* d_out, int out_size, void* d_ws, size_t ws_size,
                              hipStream_t stream) {
    (void)in_sizes; (void)n_in; (void)d_ws; (void)ws_size; (void)out_size;
    const float* freqs  = (const float*)d_in[0];
    const float* incl   = (const float*)d_in[1];
    const float* rot    = (const float*)d_in[2];
    const float* lb     = (const float*)d_in[3];
    const float* vshift = (const float*)d_in[4];
    const float* vmax   = (const float*)d_in[5];
    const float* rturn  = (const float*)d_in[6];
    const float* i0     = (const float*)d_in[7];
    const float* rd     = (const float*)d_in[8];
    const float* hz     = (const float*)d_in[9];
    float* out = (float*)d_out;

    dim3 grid(IMG_OUT, IMG_OUT);
    dim3 block(128);
    hipLaunchKernelGGL(cube_sim_kernel, grid, block, 0, stream,
                       freqs, incl, rot, lb, vshift, vmax, rturn, i0, rd, hz, out);
}

// Round 6
// 13.228 us; speedup vs baseline: 1.3503x; 1.3503x over previous
//
#include <hip/hip_runtime.h>
#include <math.h>

#define IMG_OUT 64
#define WIN 14          // per-lane band window (fine channels)
#define PSTRIDE 17      // LDS row stride (words); rows 32 apart alias 2-way = free

__global__ __launch_bounds__(64) void cube_sim_kernel(
    const float* __restrict__ freqs,
    const float* __restrict__ p_incl,
    const float* __restrict__ p_rot,
    const float* __restrict__ p_lb,
    const float* __restrict__ p_vshift,
    const float* __restrict__ p_vmax,
    const float* __restrict__ p_rturn,
    const float* __restrict__ p_i0,
    const float* __restrict__ p_rd,
    const float* __restrict__ p_hz,
    float* __restrict__ out)
{
    const int lane = threadIdx.x;      // 0..63
    const int xo = blockIdx.x, yo = blockIdx.y;
    const int p  = lane >> 4;          // internal pixel 0..3
    const int zb = lane & 15;          // z-block (8 z each)

    __shared__ float s_P[64 * PSTRIDE + 4];   // per-row prefix sums (15 entries)

    // ---- scalars (uniform -> s_load) ----
    const float incl   = p_incl[0];
    const float rot    = p_rot[0];
    const float lb     = p_lb[0];
    const float vshift = p_vshift[0];
    const float vmx    = p_vmax[0];
    const float rturn  = p_rturn[0];
    const float i0     = p_i0[0];
    const float rd     = p_rd[0];
    const float hz     = p_hz[0];

    const float LOG2E = 1.4426950408889634f;
    const float ci = __cosf(incl), si = __sinf(incl);
    const float cr = __cosf(rot),  sr = __sinf(rot);

    const float K1   = 299792.458f / 230.538f;      // C_KMS / F_REST (folded)
    const float f_lo = freqs[0];
    const float df   = (freqs[15] - f_lo) * (1.0f / 63.0f);
    const float beta = K1 * df;                     // km/s per fine channel
    const float alpha = 299792.458f - K1 * (f_lo - 2.0f * df) - vshift;
    const float inv_beta = __builtin_amdgcn_rcpf(beta);

    const float rlb = __builtin_amdgcn_rcpf(lb);
    const float sgs = 1.20112240878645f * rlb;      // sqrt(log2 e)/lb
    const float bp  = beta * sgs;                   // channel pitch, d' units

    const float step  = 2000.0f / 127.0f;
    const float invrt = __builtin_amdgcn_rcpf(rturn);
    const float cA_r  = -LOG2E * __builtin_amdgcn_rcpf(rd);
    const float cA_z  = -LOG2E * __builtin_amdgcn_rcpf(hz);

    // ---- geometry: this lane's pixel, 8 z-points ----
    const float x = -1000.0f + (float)(2 * xo + (p >> 1)) * step;
    const float y = -1000.0f + (float)(2 * yo + (p & 1)) * step;
    const float rx   = cr * x - sr * y;
    const float u0   = sr * x + cr * y;
    const float crx  = -si * vmx * 0.636619772367581f * rx;  // v = crx*atan(t)/rad
    const float rx2e = fmaf(rx, rx, 1e-12f);
    const float zb0  = -1000.0f + (float)(zb * 8) * step;

    float v[8], A[8];
    #pragma unroll
    for (int k = 0; k < 8; ++k) {
        const float z  = zb0 + (float)k * step;
        const float ry = ci * u0 - si * z;
        const float rz = si * u0 + ci * z;
        const float r2 = fmaf(ry, ry, rx2e);
        const float ir = __builtin_amdgcn_rsqf(r2);
        const float rad = r2 * ir;
        // cheap atan: tm = min(t, 1/t); A&S 5-coef poly (err ~1e-5 rad); reflect
        const float tg = rad * invrt;
        const float tm = fminf(tg, __builtin_amdgcn_rcpf(tg));
        const float x2 = tm * tm;
        float pl = fmaf(x2, 0.0208351f, -0.0851330f);
        pl = fmaf(x2, pl, 0.1801410f);
        pl = fmaf(x2, pl, -0.3302995f);
        pl = fmaf(x2, pl, 0.9998660f);
        pl *= tm;
        const float at = (tg > 1.0f) ? (1.57079632679f - pl) : pl;
        v[k] = crx * at * ir;                               // v_los
        A[k] = fmaf(rad, cA_r, fabsf(rz) * cA_z);           // log2 intensity
    }

    // ---- per-lane band base (floor-centering -> symmetric +-6.5ch coverage) ----
    float vlo = v[0], vhi = v[0];
    #pragma unroll
    for (int k = 1; k < 8; ++k) { vlo = fminf(vlo, v[k]); vhi = fmaxf(vhi, v[k]); }
    const float mid = 0.5f * (vlo + vhi);
    int basei = (int)floorf((alpha - mid) * inv_beta) - 6;
    basei = min(max(basei, 0), 64 - WIN);
    const float Wb = fmaf(-beta, (float)basei, alpha);

    // ---- 8z x 14ch KDE, register-resident ----
    float acc[WIN];
    #pragma unroll
    for (int j = 0; j < WIN; ++j) acc[j] = 0.0f;

    #pragma unroll
    for (int k = 0; k < 8; ++k) {
        const float Wk = sgs * (Wb - v[k]);
        const float Ak = A[k];
        #pragma unroll
        for (int j = 0; j < WIN; ++j) {
            const float d = fmaf(-bp, (float)j, Wk);
            acc[j] += __builtin_amdgcn_exp2f(fmaf(-d, d, Ak));
        }
    }

    // ---- publish prefix sums: P[0]=0, P[j+1]=P[j]+acc[j] ----
    const int rowb = lane * PSTRIDE;
    float P = 0.0f;
    s_P[rowb] = 0.0f;
    #pragma unroll
    for (int j = 0; j < WIN; ++j) { P += acc[j]; s_P[rowb + j + 1] = P; }
    __syncthreads();

    // ---- gather: 4 lanes per coarse channel, 16 rows each, via P[hi]-P[lo] ----
    const int t16 = lane & 15;           // coarse channel
    const int g   = lane >> 4;           // row group
    const int c4  = t16 * 4;             // first fine channel of coarse t16
    float s = 0.0f;
    #pragma unroll
    for (int i = 0; i < 16; ++i) {
        const int r = g * 16 + i;
        const int b = __shfl(basei, r);
        int lo = c4 - b;
        int hi = lo + 4;
        lo = min(max(lo, 0), WIN);
        hi = min(max(hi, 0), WIN);
        s += s_P[r * PSTRIDE + hi] - s_P[r * PSTRIDE + lo];
    }
    s += __shfl_xor(s, 16);
    s += __shfl_xor(s, 32);

    if (lane < 16) {
        // 1/16 pool * i0 / sqrt(2*pi*lb^2)
        const float scale = i0 * 0.0625f * 0.3989422804014327f * rlb;
        out[t16 * (IMG_OUT * IMG_OUT) + xo * IMG_OUT + yo] = s * scale;
    }
}

extern "C" void kernel_launch(void* const* d_in, const int* in_sizes, int n_in,
                              void* d_out, int out_size, void* d_ws, size_t ws_size,
                              hipStream_t stream) {
    (void)in_sizes; (void)n_in; (void)d_ws; (void)ws_size; (void)out_size;
    const float* freqs  = (const float*)d_in[0];
    const float* incl   = (const float*)d_in[1];
    const float* rot    = (const float*)d_in[2];
    const float* lb     = (const float*)d_in[3];
    const float* vshift = (const float*)d_in[4];
    const float* vmax   = (const float*)d_in[5];
    const float* rturn  = (const float*)d_in[6];
    const float* i0     = (const float*)d_in[7];
    const float* rd     = (const float*)d_in[8];
    const float* hz     = (const float*)d_in[9];
    float* out = (float*)d_out;

    dim3 grid(IMG_OUT, IMG_OUT);
    dim3 block(64);
    hipLaunchKernelGGL(cube_sim_kernel, grid, block, 0, stream,
                       freqs, incl, rot, lb, vshift, vmax, rturn, i0, rd, hz, out);
}